// Round 5
// baseline (48.979 us; speedup 1.0000x reference)
//
#include <hip/hip_runtime.h>

#define BATCH  8192
#define GROUPS 512
#define OUT_D  8
#define BT     64              // batch rows per wave (lane = row)
#define GT     16              // groups per block (4 waves x 4 groups)
#define NGT    (GROUPS / GT)   // 32 group tiles
#define WROW   5               // float4 units per staging row (4 data + 1 pad)

// Barrier-free design: each of the 4 waves is fully independent.
// Wave w owns groups gt*16 + w*4 .. +3 for 64 consecutive batch rows
// (lane = batch row). Param gathers: all 64 lanes hit the SAME group's
// 864B region, and gt = blockIdx.x % 32 keeps that region L1-resident
// (co-resident blocks on a CU share the same group tile).
// Output goes through a PER-WAVE 5KB LDS staging region (2 rounds of
// 2 groups), ordered by wave-internal lgkmcnt only -> no __syncthreads,
// waves slip freely, 20KB/block -> 8 blocks/CU = 100% occupancy.
__global__ __launch_bounds__(256, 8) void hoact_kernel(
    const float* __restrict__ X,
    const float* __restrict__ P,
    float* __restrict__ out)
{
    __shared__ float4 s[4][BT * WROW];   // 4 x 5KB = 20KB

    const int gt = blockIdx.x % NGT;     // group tile (L1 residency key)
    const int bt = blockIdx.x / NGT;     // batch tile 0..127

    const int lane = threadIdx.x & 63;
    const int w    = threadIdx.x >> 6;

    const int b     = bt * BT + lane;
    const int gbase = gt * GT + w * 4;

    // direct X load: 12 contiguous floats (16B-aligned; g0*12B % 48 == 0)
    const float* xp = X + (size_t)b * (GROUPS * 3) + (size_t)gbase * 3;
    float4 v0 = *(const float4*)(xp + 0);
    float4 v1 = *(const float4*)(xp + 4);
    float4 v2 = *(const float4*)(xp + 8);
    float a[12] = {v0.x, v0.y, v0.z, v0.w,
                   v1.x, v1.y, v1.z, v1.w,
                   v2.x, v2.y, v2.z, v2.w};

    float4* out4 = (float4*)out;
    const size_t row_u = GROUPS * OUT_D / 4;   // 1024 float4 per out row

    #pragma unroll
    for (int rnd = 0; rnd < 2; ++rnd) {
        // ---- compute 2 groups, stage into this wave's LDS region ----
        #pragma unroll
        for (int gh = 0; gh < 2; ++gh) {
            int gi = rnd * 2 + gh;
            float x0 = a[gi*3+0], x1 = a[gi*3+1], x2 = a[gi*3+2];
            float b0 = fabsf(x0), b1 = fabsf(x1), b2 = fabsf(x2);
            int t0 = (x0 >= 0.f) ? 1 : -1;
            int t1 = (x1 >= 0.f) ? 3 : -3;
            int t2 = (x2 >= 0.f) ? 9 : -9;
            // sort ascending by |x| (ties don't affect the result)
            if (b0 > b1) { float tb=b0; b0=b1; b1=tb; int tt=t0; t0=t1; t1=tt; }
            if (b1 > b2) { float tb=b1; b1=b2; b2=tb; int tt=t1; t1=t2; t2=tt; }
            if (b0 > b1) { float tb=b0; b0=b1; b1=tb; int tt=t0; t0=t1; t1=tt; }
            int i2 = t2 + 13;
            int i1 = t1 + t2 + 13;
            int i0 = t0 + t1 + t2 + 13;
            float c0 = b0;
            float c1 = b1 - b0;
            float c2 = b2 - b1;

            const float* pg = P + (size_t)(gbase + gi) * (27 * OUT_D);
            const float4* p0 = (const float4*)(pg + i0 * OUT_D);
            const float4* p1 = (const float4*)(pg + i1 * OUT_D);
            const float4* p2 = (const float4*)(pg + i2 * OUT_D);
            float4 q0l = p0[0], q0h = p0[1];
            float4 q1l = p1[0], q1h = p1[1];
            float4 q2l = p2[0], q2h = p2[1];

            float4 lo, hi;
            lo.x = c0*q0l.x + c1*q1l.x + c2*q2l.x;
            lo.y = c0*q0l.y + c1*q1l.y + c2*q2l.y;
            lo.z = c0*q0l.z + c1*q1l.z + c2*q2l.z;
            lo.w = c0*q0l.w + c1*q1l.w + c2*q2l.w;
            hi.x = c0*q0h.x + c1*q1h.x + c2*q2h.x;
            hi.y = c0*q0h.y + c1*q1h.y + c2*q2h.y;
            hi.z = c0*q0h.z + c1*q1h.z + c2*q2h.z;
            hi.w = c0*q0h.w + c1*q1h.w + c2*q2h.w;

            s[w][lane * WROW + gh * 2 + 0] = lo;
            s[w][lane * WROW + gh * 2 + 1] = hi;
        }

        // ---- wave-local store: lanes contiguous along the group axis ----
        // 4 lanes cover one row's 4 units (64B line); 16 rows per instr.
        const size_t col0 = (size_t)gt * (GT * OUT_D / 4) + w * 8 + rnd * 4;
        #pragma unroll
        for (int k = 0; k < 4; ++k) {
            int u = lane + 64 * k;       // 0..255
            int r = u >> 2;              // tile row 0..63
            int f = u & 3;               // col unit 0..3
            float4 val = s[w][r * WROW + f];
            out4[(size_t)(bt * BT + r) * row_u + col0 + f] = val;
        }
    }
}

extern "C" void kernel_launch(void* const* d_in, const int* in_sizes, int n_in,
                              void* d_out, int out_size, void* d_ws, size_t ws_size,
                              hipStream_t stream) {
    const float* X = (const float*)d_in[0];
    const float* P = (const float*)d_in[1];
    float* out = (float*)d_out;

    const int grid = (BATCH / BT) * NGT;  // 128 * 32 = 4096
    hoact_kernel<<<grid, 256, 0, stream>>>(X, P, out);
}

// Round 6
// 44.942 us; speedup vs baseline: 1.0898x; 1.0898x over previous
//
#include <hip/hip_runtime.h>

typedef float vf4 __attribute__((ext_vector_type(4)));

#define BATCH  8192
#define GROUPS 512
#define OUT_D  8
#define RT     16              // batch rows per block
#define GB     64              // groups per block
#define NGT    (GROUPS / GB)   // 8 group tiles

// Write-locality-optimized tiling: block owns 16 rows x 64 groups, so its
// output is 16 spans of 2KB CONTIGUOUS (vs 64 spans of 512B before) --
// much better DRAM page locality on the dominant 134MB write stream.
// Stores are nontemporal (write-once; keep X/params in cache).
// Gathers: 16 lanes share each group's 864B param region (4 regions/instr).
// Output staged in 32KB LDS with XOR swizzle (2-way worst = free).
__global__ __launch_bounds__(256) void hoact_kernel(
    const float* __restrict__ X,
    const float* __restrict__ P,
    float* __restrict__ out)
{
    __shared__ vf4 stage[RT * 128];      // 16 rows x 128 float4 units = 32KB

    const int gt = blockIdx.x % NGT;     // 0..7
    const int bt = blockIdx.x / NGT;     // 0..511

    const int tid  = threadIdx.x;
    const int w    = tid >> 6;           // wave 0..3
    const int lane = tid & 63;
    const int row  = lane & 15;          // tile row 0..15
    const int gch  = lane >> 4;          // group chunk 0..3

    const int g_local0 = w * 16 + gch * 4;     // first of this thread's 4 groups
    const int b = bt * RT + row;

    // 12 contiguous floats (16B-aligned: group index multiple of 4)
    const float* xp = X + (size_t)b * (GROUPS * 3)
                        + (size_t)(gt * GB + g_local0) * 3;
    float4 v0 = *(const float4*)(xp + 0);
    float4 v1 = *(const float4*)(xp + 4);
    float4 v2 = *(const float4*)(xp + 8);
    float a[12] = {v0.x, v0.y, v0.z, v0.w,
                   v1.x, v1.y, v1.z, v1.w,
                   v2.x, v2.y, v2.z, v2.w};

    const int sw = row;                  // XOR swizzle key (0..15)

    #pragma unroll
    for (int gi = 0; gi < 4; ++gi) {
        float x0 = a[gi*3+0], x1 = a[gi*3+1], x2 = a[gi*3+2];
        float b0 = fabsf(x0), b1 = fabsf(x1), b2 = fabsf(x2);
        int t0 = (x0 >= 0.f) ? 1 : -1;
        int t1 = (x1 >= 0.f) ? 3 : -3;
        int t2 = (x2 >= 0.f) ? 9 : -9;
        // sort ascending by |x| (ties don't affect the result)
        if (b0 > b1) { float tb=b0; b0=b1; b1=tb; int tt=t0; t0=t1; t1=tt; }
        if (b1 > b2) { float tb=b1; b1=b2; b2=tb; int tt=t1; t1=t2; t2=tt; }
        if (b0 > b1) { float tb=b0; b0=b1; b1=tb; int tt=t0; t0=t1; t1=tt; }
        int i2 = t2 + 13;
        int i1 = t1 + t2 + 13;
        int i0 = t0 + t1 + t2 + 13;
        float c0 = b0;
        float c1 = b1 - b0;
        float c2 = b2 - b1;

        const float* pg = P + (size_t)(gt * GB + g_local0 + gi) * (27 * OUT_D);
        const float4* p0 = (const float4*)(pg + i0 * OUT_D);
        const float4* p1 = (const float4*)(pg + i1 * OUT_D);
        const float4* p2 = (const float4*)(pg + i2 * OUT_D);
        float4 q0l = p0[0], q0h = p0[1];
        float4 q1l = p1[0], q1h = p1[1];
        float4 q2l = p2[0], q2h = p2[1];

        vf4 lo, hi;
        lo.x = c0*q0l.x + c1*q1l.x + c2*q2l.x;
        lo.y = c0*q0l.y + c1*q1l.y + c2*q2l.y;
        lo.z = c0*q0l.z + c1*q1l.z + c2*q2l.z;
        lo.w = c0*q0l.w + c1*q1l.w + c2*q2l.w;
        hi.x = c0*q0h.x + c1*q1h.x + c2*q2h.x;
        hi.y = c0*q0h.y + c1*q1h.y + c2*q2h.y;
        hi.z = c0*q0h.z + c1*q1h.z + c2*q2h.z;
        hi.w = c0*q0h.w + c1*q1h.w + c2*q2h.w;

        int u = (g_local0 + gi) * 2;     // logical unit 0..127
        stage[row * 128 + ((u    ) ^ sw)] = lo;
        stage[row * 128 + ((u + 1) ^ sw)] = hi;
    }

    __syncthreads();

    // Store 16 rows x 2KB contiguous spans. Each wave-instruction writes
    // 1KB contiguous; waves 0/1 cover row 2k, waves 2/3 cover row 2k+1.
    vf4* out4 = (vf4*)out;
    const size_t row_u = GROUPS * OUT_D / 4;   // 1024 units per out row
    const size_t col0  = (size_t)gt * 128;     // 64 groups * 8 / 4
    #pragma unroll
    for (int k = 0; k < 8; ++k) {
        int u = tid + 256 * k;           // 0..2047
        int r = u >> 7;                  // tile row 0..15
        int f = u & 127;                 // unit within 2KB span
        vf4 val = stage[r * 128 + (f ^ r)];
        __builtin_nontemporal_store(
            val, &out4[(size_t)(bt * RT + r) * row_u + col0 + f]);
    }
}

extern "C" void kernel_launch(void* const* d_in, const int* in_sizes, int n_in,
                              void* d_out, int out_size, void* d_ws, size_t ws_size,
                              hipStream_t stream) {
    const float* X = (const float*)d_in[0];
    const float* P = (const float*)d_in[1];
    float* out = (float*)d_out;

    const int grid = (BATCH / RT) * NGT;  // 512 * 8 = 4096
    hoact_kernel<<<grid, 256, 0, stream>>>(X, P, out);
}